// Round 7
// baseline (425.362 us; speedup 1.0000x reference)
//
#include <hip/hip_runtime.h>
#include <hip/hip_bf16.h>

#define B_      64
#define S_      4096
#define DIM_    256
#define DA_     64
#define NEG_    (-1e30f)
#define LDH_    264           // halves per LDS row (256 + 8 pad)
#define PSTR_   264           // partial stride: m, l, pad, pad, o[256], pad4 (1056 B)

typedef _Float16 half8 __attribute__((ext_vector_type(8)));
typedef float float4v __attribute__((ext_vector_type(4)));

// tanh(x) = 1 - 2/(exp(2x)+1); exact at +/-inf; err ~1e-6 << 2e-3 tol.
__device__ __forceinline__ float tanh_fast(float x) {
    float e = __expf(2.0f * x);
    return 1.0f - 2.0f * __builtin_amdgcn_rcpf(e + 1.0f);
}

// Kernel 0 (unchanged): A (DIM x DA fp32) -> fp16 swizzled into MFMA A-fragment
// order; detect mask encoding (flag=1 => int32 elements, flag=0 => 1-byte).
// at_sw index: ((nt*8+kb)*64 + lane)*8 + j = a[d][n],
//   d = kb*32 + (lane>>4)*8 + j, n = nt*16 + (lane&15)
__global__ __launch_bounds__(256) void prep_kernel(
    const float* __restrict__ a, const void* __restrict__ mask,
    _Float16* __restrict__ at_sw, int* __restrict__ flag)
{
    int idx = blockIdx.x * 256 + threadIdx.x;   // 0..16383
    int j    = idx & 7;
    int lane = (idx >> 3) & 63;
    int kbnt = idx >> 9;
    int kb   = kbnt & 7;
    int nt   = kbnt >> 3;
    int d  = kb * 32 + (lane >> 4) * 8 + j;
    int kf = nt * 16 + (lane & 15);
    at_sw[idx] = (_Float16)a[d * DA_ + kf];

    if (blockIdx.x == 0) {
        __shared__ int anynz;
        if (threadIdx.x == 0) anynz = 0;
        __syncthreads();
        const unsigned char* mb = (const unsigned char*)mask;
        int base = threadIdx.x * 4;   // scan first 1024 bytes
        int v = mb[base + 1] | mb[base + 2] | mb[base + 3];
        if (v) atomicOr(&anynz, 1);
        __syncthreads();
        if (threadIdx.x == 0) *flag = (anynz == 0) ? 1 : 0;
    }
}

// R11 fused kernel: occupancy-first. All prior clean variants showed the
// latency-bound signature (VALUBusy 5-6%, MfmaUtil 1.5%, HBM ~30%, Occ 21-24%)
// while capped at 8-12 waves/CU by the 32 KiB LDS asw (+34 KiB h tile).
// Changes vs R10:
//  - a-fragments read DIRECTLY from global at_sw per MFMA (lane-coalesced
//    1 KiB/wave reads of a 32 KiB read-only array -> L1/L2-resident; zero
//    LDS, zero per-block prologue, zero barriers anywhere).
//  - 128-thread blocks = 2 independent waves, each owning a 16-row task and
//    its own LDS half. LDS 16.9 KiB/block; __launch_bounds__(128,4) ->
//    8 blocks/CU = 16 waves/CU (2x R10, 4x R6).
//  - per-wave body identical to R10 (proven no-spill: hv[8] phase-local,
//    accm[4], acc0..3; R5/R7/R9 rule: no >=16-reg array live across MFMA).
__global__ __launch_bounds__(128, 4) void fused_kernel(
    const float* __restrict__ h, const _Float16* __restrict__ at_sw,
    const float* __restrict__ bvec, const void* __restrict__ mask,
    const int* __restrict__ flag, float* __restrict__ part)
{
    __shared__ _Float16 hf[32 * LDH_];   // 16,896 B; two wave-private 16-row halves

    const int t    = threadIdx.x;
    const int wave = t >> 6;             // 0..1
    const int lane = t & 63;
    const int quad = lane >> 4;
    const int nrow = lane & 15;
    const bool int32enc = (*flag != 0);

    float4 bq[4];
    #pragma unroll
    for (int nt = 0; nt < 4; ++nt)
        bq[nt] = *(const float4*)(bvec + nt * 16 + quad * 4);

    const int bid = blockIdx.x;          // 8192 blocks: batch = bid>>7, grp = bid&127
    const long long rowg = ((long long)(bid >> 7) * S_)
                         + (long long)(bid & 127) * 32 + wave * 16 + nrow;
    const float* hp = h + rowg * DIM_ + quad * 8;   // own row, own quad offset

    // own-row mask (uniform across quads), issued before the h loads
    int mv = int32enc ? ((const int*)mask)[rowg]
                      : (int)((const unsigned char*)mask)[rowg];

    const int lrow = wave * 16 + nrow;   // own LDS row
    float4v accm[4];
    #pragma unroll
    for (int nt = 0; nt < 4; ++nt) accm[nt] = (float4v){0.f, 0.f, 0.f, 0.f};

    // two half-phases: 8 independent float4 loads, then cvt + LDS write-through
    // + MFMA with a-fragments streamed from L1/L2 (hv dies inside the phase)
    #pragma unroll
    for (int kh = 0; kh < 2; ++kh) {
        float4 hv[8];
        #pragma unroll
        for (int i = 0; i < 8; ++i) {
            int kb = kh * 4 + (i >> 1);
            hv[i] = *(const float4*)(hp + kb * 32 + (i & 1) * 4);
        }
        #pragma unroll
        for (int k = 0; k < 4; ++k) {
            int kb = kh * 4 + k;
            union { _Float16 hh[8]; half8 v; } pk;
            pk.hh[0] = (_Float16)hv[2 * k].x;     pk.hh[1] = (_Float16)hv[2 * k].y;
            pk.hh[2] = (_Float16)hv[2 * k].z;     pk.hh[3] = (_Float16)hv[2 * k].w;
            pk.hh[4] = (_Float16)hv[2 * k + 1].x; pk.hh[5] = (_Float16)hv[2 * k + 1].y;
            pk.hh[6] = (_Float16)hv[2 * k + 1].z; pk.hh[7] = (_Float16)hv[2 * k + 1].w;
            // write-through for the accumulate phase (own row slice)
            *(half8*)&hf[lrow * LDH_ + kb * 32 + quad * 8] = pk.v;
            #pragma unroll
            for (int nt = 0; nt < 4; ++nt) {
                half8 af = *(const half8*)(at_sw + ((nt * 8 + kb) * 64 + lane) * 8);
                accm[nt] = __builtin_amdgcn_mfma_f32_16x16x32_f16(af, pk.v, accm[nt], 0, 0, 0);
            }
        }
    }

    // e[own row]: lane holds n = nt*16 + quad*4 + r; reduce over quads
    float p = 0.f;
    #pragma unroll
    for (int nt = 0; nt < 4; ++nt) {
        p += tanh_fast(accm[nt][0]) * bq[nt].x;
        p += tanh_fast(accm[nt][1]) * bq[nt].y;
        p += tanh_fast(accm[nt][2]) * bq[nt].z;
        p += tanh_fast(accm[nt][3]) * bq[nt].w;
    }
    p += __shfl_xor(p, 16);
    p += __shfl_xor(p, 32);              // uniform across quads

    // per-wave single-tile softmax over its 16 rows (no online carry)
    float ev = mv ? NEG_ : p;
    float mx = ev;
    mx = fmaxf(mx, __shfl_xor(mx, 1));
    mx = fmaxf(mx, __shfl_xor(mx, 2));
    mx = fmaxf(mx, __shfl_xor(mx, 4));
    mx = fmaxf(mx, __shfl_xor(mx, 8));
    float w_s = __expf(ev - mx);         // all-masked group: w=1, zeroed at merge
    float sm = w_s;
    sm += __shfl_xor(sm, 1);
    sm += __shfl_xor(sm, 2);
    sm += __shfl_xor(sm, 4);
    sm += __shfl_xor(sm, 8);

    // accumulate own 4 dims over the wave's 16 rows (fp16 LDS, same-wave order
    // guaranteed by compiler lgkmcnt -> still no barrier)
    float acc0 = 0.f, acc1 = 0.f, acc2 = 0.f, acc3 = 0.f;
    #pragma unroll
    for (int s = 0; s < 16; ++s) {
        float wv = __shfl(w_s, s);       // row-group row s's weight (v_readlane)
        union { ushort4 u; _Float16 hh[4]; } pk;
        pk.u = *(const ushort4*)((const unsigned short*)
                   &hf[(wave * 16 + s) * LDH_ + lane * 4]);
        acc0 = fmaf(wv, (float)pk.hh[0], acc0);
        acc1 = fmaf(wv, (float)pk.hh[1], acc1);
        acc2 = fmaf(wv, (float)pk.hh[2], acc2);
        acc3 = fmaf(wv, (float)pk.hh[3], acc3);
    }

    // per-(16-row-group) partial
    float* pc = part + (size_t)(bid * 2 + wave) * PSTR_;
    *(float4*)(pc + 4 + lane * 4) = make_float4(acc0, acc1, acc2, acc3);
    if (lane == 0) { pc[0] = mx; pc[1] = sm; }
}

// Kernel 2: merge 256 per-group partials per batch -> out[b][d]
__global__ __launch_bounds__(256) void merge_kernel(
    const float* __restrict__ part, float* __restrict__ out)
{
    const int b = blockIdx.x;
    const int t = threadIdx.x;
    const float* pb = part + (size_t)b * 256 * PSTR_;
    float M = NEG_;
    #pragma unroll 8
    for (int i = 0; i < 256; ++i) M = fmaxf(M, pb[i * PSTR_]);
    float L = 0.f, o = 0.f;
    #pragma unroll 8
    for (int i = 0; i < 256; ++i) {
        float sc = __expf(pb[i * PSTR_] - M);
        L += pb[i * PSTR_ + 1] * sc;
        o += pb[i * PSTR_ + 4 + t] * sc;
    }
    out[b * DIM_ + t] = o / L;
}

extern "C" void kernel_launch(void* const* d_in, const int* in_sizes, int n_in,
                              void* d_out, int out_size, void* d_ws, size_t ws_size,
                              hipStream_t stream) {
    const float* h    = (const float*)d_in[0];
    const void*  mask = d_in[1];
    const float* a    = (const float*)d_in[2];
    const float* bvec = (const float*)d_in[3];
    float* out = (float*)d_out;

    char* ws = (char*)d_ws;
    _Float16* at_sw = (_Float16*)ws;              // 32,768 B
    int* flag       = (int*)(ws + 32768);
    float* part     = (float*)(ws + 36864);       // 16384 * 1056 B ~= 17.3 MiB

    prep_kernel<<<64, 256, 0, stream>>>(a, mask, at_sw, flag);
    fused_kernel<<<B_ * 128, 128, 0, stream>>>(h, at_sw, bvec, mask, flag, part);
    merge_kernel<<<B_, 256, 0, stream>>>(part, out);
}

// Round 8
// 371.808 us; speedup vs baseline: 1.1440x; 1.1440x over previous
//
#include <hip/hip_runtime.h>
#include <hip/hip_bf16.h>

#define B_      64
#define S_      4096
#define DIM_    256
#define DA_     64
#define NEG_    (-1e30f)
#define CHUNKS_ 16
#define ROWS_   256           // seq rows per chunk (4 tiles x 64)
#define LDW_    260           // floats per LDS row (256 + 4 pad)
#define PSTR_   264           // partial stride: m, l, pad, pad, o[256], pad4 (1056 B)

typedef _Float16 half8 __attribute__((ext_vector_type(8)));
typedef float float4v __attribute__((ext_vector_type(4)));

// tanh(x) = 1 - 2/(exp(2x)+1); exact at +/-inf; err ~1e-6 << 2e-3 tol.
__device__ __forceinline__ float tanh_fast(float x) {
    float e = __expf(2.0f * x);
    return 1.0f - 2.0f * __builtin_amdgcn_rcpf(e + 1.0f);
}

// Kernel 0 (unchanged): A (DIM x DA fp32) -> fp16 swizzled into MFMA A-fragment
// order; detect mask encoding (flag=1 => int32 elements, flag=0 => 1-byte).
// at_sw index: ((nt*8+kb)*64 + lane)*8 + j = a[d][n],
//   d = kb*32 + (lane>>4)*8 + j, n = nt*16 + (lane&15)
__global__ __launch_bounds__(256) void prep_kernel(
    const float* __restrict__ a, const void* __restrict__ mask,
    _Float16* __restrict__ at_sw, int* __restrict__ flag)
{
    int idx = blockIdx.x * 256 + threadIdx.x;   // 0..16383
    int j    = idx & 7;
    int lane = (idx >> 3) & 63;
    int kbnt = idx >> 9;
    int kb   = kbnt & 7;
    int nt   = kbnt >> 3;
    int d  = kb * 32 + (lane >> 4) * 8 + j;
    int kf = nt * 16 + (lane & 15);
    at_sw[idx] = (_Float16)a[d * DA_ + kf];

    if (blockIdx.x == 0) {
        __shared__ int anynz;
        if (threadIdx.x == 0) anynz = 0;
        __syncthreads();
        const unsigned char* mb = (const unsigned char*)mask;
        int base = threadIdx.x * 4;   // scan first 1024 bytes
        int v = mb[base + 1] | mb[base + 2] | mb[base + 3];
        if (v) atomicOr(&anynz, 1);
        __syncthreads();
        if (threadIdx.x == 0) *flag = (anynz == 0) ? 1 : 0;
    }
}

// R12 fused kernel: R6's structure (best measured: wave-private rows,
// global_load_lds staging, zero main-loop barriers, per-wave online softmax)
// with its one defect fixed: 133 KiB fp32 dbuf -> SINGLE 66.5 KiB buffer =>
// 2 blocks/CU, 8 waves/CU (R6 had 1 wave/SIMD; every stage-wait was exposed).
// Intra-wave dbuf overlap is replaced by cross-wave/cross-block overlap:
// per CU per round 8 wave-tasks x 16 KiB = 128 KiB at 10.25 B/cyc = 12.5k cyc
// vs ~3.6k cyc compute per SIMD -> memory-bound, waves self-stagger.
// a-fragments: per-MFMA global reads of at_sw (32 KiB = L1-sized, both blocks
// share it -> resident; R0 proved af-from-memory ~= af-in-regs). No reg array
// bigger than accm[4] -> no spill surface (R5/R7/R9 rule).
#define STAGE(tile_) do {                                                       \
    const float* sp_ = h + (crow + (tile_) * 64 + wave * 16) * DIM_ + lane * 4; \
    _Pragma("unroll")                                                           \
    for (int i_ = 0; i_ < 16; ++i_) {                                           \
        __builtin_amdgcn_global_load_lds(                                       \
            (__attribute__((address_space(1))) void*)(sp_ + (size_t)i_ * DIM_), \
            (__attribute__((address_space(3))) void*)&buf[wave * 16 + i_][0],   \
            16, 0, 0);                                                          \
    }                                                                           \
} while (0)

__global__ __launch_bounds__(256, 2) void fused_kernel(
    const float* __restrict__ h, const _Float16* __restrict__ at_sw,
    const float* __restrict__ bvec, const void* __restrict__ mask,
    const int* __restrict__ flag, float* __restrict__ part)
{
    __shared__ float buf[64][LDW_];      // 66,560 B -> 2 blocks/CU

    const int t    = threadIdx.x;
    const int wave = t >> 6;
    const int lane = t & 63;
    const int quad = lane >> 4;
    const int nrow = lane & 15;
    const bool int32enc = (*flag != 0);

    float4 bq[4];
    #pragma unroll
    for (int nt = 0; nt < 4; ++nt)
        bq[nt] = *(const float4*)(bvec + nt * 16 + quad * 4);

    const int cg = blockIdx.x;           // chunk id, 0..1023
    const long long crow = (long long)(cg >> 4) * S_ + (cg & 15) * ROWS_;
    const long long row0 = crow + wave * 16 + nrow;   // this lane's tile-0 row

    // prefetch all 4 tile masks up front (no per-tile mask stall)
    int mv0, mv1, mv2, mv3;
    if (int32enc) {
        const int* mi = (const int*)mask + row0;
        mv0 = mi[0]; mv1 = mi[64]; mv2 = mi[128]; mv3 = mi[192];
    } else {
        const unsigned char* mb = (const unsigned char*)mask + row0;
        mv0 = mb[0]; mv1 = mb[64]; mv2 = mb[128]; mv3 = mb[192];
    }

    float acc0 = 0.f, acc1 = 0.f, acc2 = 0.f, acc3 = 0.f;
    float m_w = NEG_, l_w = 0.f;

    auto body = [&](int tile, int mv) {
        // ---- stage own 16 rows fp32 -> LDS (wave-private; no barrier) ----
        STAGE(tile);
        asm volatile("s_waitcnt vmcnt(0)" ::: "memory");
        __builtin_amdgcn_sched_barrier(0);

        // ---- MFMA: z^T[n][own row]; B-frag = own row from LDS (cvt fp16) ----
        const float* hrow_l = &buf[wave * 16 + nrow][0];
        float4v accm[4];
        #pragma unroll
        for (int nt = 0; nt < 4; ++nt) accm[nt] = (float4v){0.f, 0.f, 0.f, 0.f};
        #pragma unroll
        for (int kb = 0; kb < 8; ++kb) {
            float4 ha  = *(const float4*)(hrow_l + kb * 32 + quad * 8);
            float4 hb2 = *(const float4*)(hrow_l + kb * 32 + quad * 8 + 4);
            union { _Float16 hh[8]; half8 v; } pk;
            pk.hh[0] = (_Float16)ha.x;  pk.hh[1] = (_Float16)ha.y;
            pk.hh[2] = (_Float16)ha.z;  pk.hh[3] = (_Float16)ha.w;
            pk.hh[4] = (_Float16)hb2.x; pk.hh[5] = (_Float16)hb2.y;
            pk.hh[6] = (_Float16)hb2.z; pk.hh[7] = (_Float16)hb2.w;
            #pragma unroll
            for (int nt = 0; nt < 4; ++nt) {
                half8 af = *(const half8*)(at_sw + ((nt * 8 + kb) * 64 + lane) * 8);
                accm[nt] = __builtin_amdgcn_mfma_f32_16x16x32_f16(af, pk.v, accm[nt], 0, 0, 0);
            }
        }

        // ---- e[own row]: lane holds n = nt*16 + quad*4 + r; reduce quads ----
        float p = 0.f;
        #pragma unroll
        for (int nt = 0; nt < 4; ++nt) {
            p += tanh_fast(accm[nt][0]) * bq[nt].x;
            p += tanh_fast(accm[nt][1]) * bq[nt].y;
            p += tanh_fast(accm[nt][2]) * bq[nt].z;
            p += tanh_fast(accm[nt][3]) * bq[nt].w;
        }
        p += __shfl_xor(p, 16);
        p += __shfl_xor(p, 32);          // uniform across quads

        // ---- per-wave online softmax over its 16 rows ----
        float ev = mv ? NEG_ : p;
        float mx = ev;
        mx = fmaxf(mx, __shfl_xor(mx, 1));
        mx = fmaxf(mx, __shfl_xor(mx, 2));
        mx = fmaxf(mx, __shfl_xor(mx, 4));
        mx = fmaxf(mx, __shfl_xor(mx, 8));
        float m_new = fmaxf(m_w, mx);
        float rs  = __expf(m_w - m_new);     // first tile: exp(-1e30) = 0
        float w_s = __expf(ev - m_new);
        float sm = w_s;
        sm += __shfl_xor(sm, 1);
        sm += __shfl_xor(sm, 2);
        sm += __shfl_xor(sm, 4);
        sm += __shfl_xor(sm, 8);
        l_w = l_w * rs + sm;
        m_w = m_new;
        acc0 *= rs; acc1 *= rs; acc2 *= rs; acc3 *= rs;

        // ---- accumulate own 4 dims over the wave's 16 rows (fp32 LDS) ----
        #pragma unroll
        for (int s = 0; s < 16; ++s) {
            float wv = __shfl(w_s, s);       // compile-time lane => v_readlane
            float4 hv = *(const float4*)(&buf[wave * 16 + s][lane * 4]);
            acc0 = fmaf(wv, hv.x, acc0);
            acc1 = fmaf(wv, hv.y, acc1);
            acc2 = fmaf(wv, hv.z, acc2);
            acc3 = fmaf(wv, hv.w, acc3);
        }
        // next tile overwrites only THIS wave's rows, after THIS wave's
        // reads above are complete (same-wave lgkmcnt ordering) -> no barrier
    };
    body(0, mv0); body(1, mv1); body(2, mv2); body(3, mv3);

    // ---- per-wave partial: acc IS the wave's o for dims lane*4..+3 ----
    float* pc = part + (size_t)(cg * 4 + wave) * PSTR_;
    *(float4*)(pc + 4 + lane * 4) = make_float4(acc0, acc1, acc2, acc3);
    if (lane == 0) { pc[0] = m_w; pc[1] = l_w; }
}

// Kernel 2: merge 64 per-wave partials (16 chunks x 4 waves) -> out[b][d]
__global__ __launch_bounds__(256) void merge_kernel(
    const float* __restrict__ part, float* __restrict__ out)
{
    const int b = blockIdx.x;
    const int t = threadIdx.x;
    const float* pb = part + (size_t)b * 64 * PSTR_;
    float M = NEG_;
    #pragma unroll
    for (int i = 0; i < 64; ++i) M = fmaxf(M, pb[i * PSTR_]);
    float L = 0.f, o = 0.f;
    #pragma unroll
    for (int i = 0; i < 64; ++i) {
        float sc = __expf(pb[i * PSTR_] - M);
        L += pb[i * PSTR_ + 1] * sc;
        o += pb[i * PSTR_ + 4 + t] * sc;
    }
    out[b * DIM_ + t] = o / L;
}

extern "C" void kernel_launch(void* const* d_in, const int* in_sizes, int n_in,
                              void* d_out, int out_size, void* d_ws, size_t ws_size,
                              hipStream_t stream) {
    const float* h    = (const float*)d_in[0];
    const void*  mask = d_in[1];
    const float* a    = (const float*)d_in[2];
    const float* bvec = (const float*)d_in[3];
    float* out = (float*)d_out;

    char* ws = (char*)d_ws;
    _Float16* at_sw = (_Float16*)ws;              // 32,768 B
    int* flag       = (int*)(ws + 32768);
    float* part     = (float*)(ws + 36864);       // 4096 * 1056 B ~= 4.3 MiB

    prep_kernel<<<64, 256, 0, stream>>>(a, mask, at_sw, flag);
    fused_kernel<<<B_ * CHUNKS_, 256, 0, stream>>>(h, at_sw, bvec, mask, flag, part);
    merge_kernel<<<B_, 256, 0, stream>>>(part, out);
}